// Round 5
// baseline (6709.996 us; speedup 1.0000x reference)
//
#include <hip/hip_runtime.h>
#include <cstdint>

using u16 = unsigned short;
using u32 = uint32_t;

typedef __bf16 bf16x8 __attribute__((ext_vector_type(8)));
typedef float  f32x4  __attribute__((ext_vector_type(4)));

#define MFMA(a, b, c) __builtin_amdgcn_mfma_f32_16x16x32_bf16((a), (b), (c), 0, 0, 0)

// ---------------- numeric helpers ----------------
static __device__ __forceinline__ u16 f2bf(float x) {
  u32 u = __float_as_uint(x);
  u32 r = (u + 0x7FFFu + ((u >> 16) & 1u)) >> 16;   // RNE
  return (u16)r;
}

static __device__ __forceinline__ u32 rotl32(u32 v, int s) {
  return (v << s) | (v >> (32 - s));
}

// JAX threefry2x32 (20 rounds)
static __device__ __forceinline__ void threefry2x32(u32 k0, u32 k1, u32 x0, u32 x1,
                                                    u32& o0, u32& o1) {
  u32 k2 = k0 ^ k1 ^ 0x1BD11BDAu;
  x0 += k0; x1 += k1;
  x0 += x1; x1 = rotl32(x1, 13); x1 ^= x0;
  x0 += x1; x1 = rotl32(x1, 15); x1 ^= x0;
  x0 += x1; x1 = rotl32(x1, 26); x1 ^= x0;
  x0 += x1; x1 = rotl32(x1, 6);  x1 ^= x0;
  x0 += k1; x1 += k2 + 1u;
  x0 += x1; x1 = rotl32(x1, 17); x1 ^= x0;
  x0 += x1; x1 = rotl32(x1, 29); x1 ^= x0;
  x0 += x1; x1 = rotl32(x1, 16); x1 ^= x0;
  x0 += x1; x1 = rotl32(x1, 24); x1 ^= x0;
  x0 += k2; x1 += k0 + 2u;
  x0 += x1; x1 = rotl32(x1, 13); x1 ^= x0;
  x0 += x1; x1 = rotl32(x1, 15); x1 ^= x0;
  x0 += x1; x1 = rotl32(x1, 26); x1 ^= x0;
  x0 += x1; x1 = rotl32(x1, 6);  x1 ^= x0;
  x0 += k0; x1 += k1 + 3u;
  x0 += x1; x1 = rotl32(x1, 17); x1 ^= x0;
  x0 += x1; x1 = rotl32(x1, 29); x1 ^= x0;
  x0 += x1; x1 = rotl32(x1, 16); x1 ^= x0;
  x0 += x1; x1 = rotl32(x1, 24); x1 ^= x0;
  x0 += k1; x1 += k2 + 4u;
  x0 += x1; x1 = rotl32(x1, 13); x1 ^= x0;
  x0 += x1; x1 = rotl32(x1, 15); x1 ^= x0;
  x0 += x1; x1 = rotl32(x1, 26); x1 ^= x0;
  x0 += x1; x1 = rotl32(x1, 6);  x1 ^= x0;
  x0 += k2; x1 += k0 + 5u;
  o0 = x0; o1 = x1;
}

// bits -> N(0,1) exactly like jax.random.normal(f32)
static __device__ __forceinline__ float bits_to_normal(u32 bits) {
  const float lo = __uint_as_float(0xBF7FFFFFu);
  float f = __uint_as_float((bits >> 9) | 0x3F800000u) - 1.0f;
  float x = fmaxf(lo, f * 2.0f + lo);
  float w = -logf((1.0f - x) * (1.0f + x));
  float p;
  if (w < 5.0f) {
    w -= 2.5f;
    p = 2.81022636e-08f;
    p = fmaf(p, w, 3.43273939e-07f);
    p = fmaf(p, w, -3.5233877e-06f);
    p = fmaf(p, w, -4.39150654e-06f);
    p = fmaf(p, w, 0.00021858087f);
    p = fmaf(p, w, -0.00125372503f);
    p = fmaf(p, w, -0.00417768164f);
    p = fmaf(p, w, 0.246640727f);
    p = fmaf(p, w, 1.50140941f);
  } else {
    w = sqrtf(w) - 3.0f;
    p = -0.000200214257f;
    p = fmaf(p, w, 0.000100950558f);
    p = fmaf(p, w, 0.00134934322f);
    p = fmaf(p, w, -0.00367342844f);
    p = fmaf(p, w, 0.00573950773f);
    p = fmaf(p, w, -0.0076224613f);
    p = fmaf(p, w, 0.00943887047f);
    p = fmaf(p, w, 1.00167406f);
    p = fmaf(p, w, 2.83297682f);
  }
  return 1.41421356f * p * x;
}

// ---------------- S1: pack weights (transpose + f32->bf16) ----------------
__global__ __launch_bounds__(256) void s1_pack(
    const float* __restrict__ W1f, const float* __restrict__ W1g,
    const float* __restrict__ W2f, const float* __restrict__ W2g,
    u16* __restrict__ W1fT, u16* __restrict__ W1gT,
    u16* __restrict__ W2fT, u16* __restrict__ W2gT) {
  __shared__ float tile[64][65];
  const int z = blockIdx.z;
  const float* in = (z == 0) ? W1f : (z == 1) ? W1g : (z == 2) ? W2f : W2g;
  u16* out = (z == 0) ? W1fT : (z == 1) ? W1gT : (z == 2) ? W2fT : W2gT;
  const int R = (z < 2) ? 4096 : 1024;
  const int C = (z < 2) ? 1024 : 4096;
  const int rt = (z < 2) ? blockIdx.x : blockIdx.y;
  const int ct = (z < 2) ? blockIdx.y : blockIdx.x;
  const int r0 = rt * 64, c0 = ct * 64;
  const int tix = threadIdx.x;
  #pragma unroll
  for (int i = 0; i < 16; ++i) {
    int lin = i * 256 + tix;
    int row = lin >> 6, col = lin & 63;
    tile[row][col] = in[(size_t)(r0 + row) * C + c0 + col];
  }
  __syncthreads();
  #pragma unroll
  for (int i = 0; i < 16; ++i) {
    int lin = i * 256 + tix;
    int orow = lin >> 6, ocol = lin & 63;
    out[(size_t)(c0 + orow) * R + r0 + ocol] = f2bf(tile[ocol][orow]);
  }
}

// ---------------- S2: init state (M=64) + t=0 output ----------------
__global__ __launch_bounds__(256) void s2_init(
    const float* __restrict__ A0, float* __restrict__ A, u16* __restrict__ Abf,
    float* __restrict__ out) {
  const int e = blockIdx.x * 256 + threadIdx.x;   // (b, n), 64x4096
  const int n = e & 4095;
  const float a0 = A0[e];
  A[e] = a0;
  Abf[e] = f2bf(a0);
  const float sig = (n % 65 == 0) ? 0.0f : 1.0f / (1.0f + expf(-a0));
  const int b = e >> 12;
  #pragma unroll
  for (int s = 0; s < 4; ++s)
    out[((size_t)s * 4096 + b) * 4096 + n] = sig;   // (s, t=0, b, n)
}

// ---------------- dW pregen (partitionable threefry) ----------------
// step<0: all 63 steps (grid 63*32); step>=0: single step (grid 32)
__global__ __launch_bounds__(256) void dw_gen(
    const float* __restrict__ tarr, float* __restrict__ dst_base, int step_param) {
  const int bid = blockIdx.x, tix = threadIdx.x;
  const int step = (step_param < 0) ? (bid >> 5) : step_param;
  const int sub = (step_param < 0) ? (bid & 31) : bid;
  u32 k0, k1;
  threefry2x32(0u, 42u, 0u, (u32)step, k0, k1);   // split(key(42),63)[step]
  const float sdt = sqrtf(tarr[1] - tarr[0]);
  float* dst = dst_base + ((step_param < 0) ? (size_t)step * 262144 : 0);
  #pragma unroll
  for (int j = 0; j < 32; ++j) {
    u32 e = (u32)(sub * 8192 + j * 256 + tix);
    u32 y0, y1;
    threefry2x32(k0, k1, 0u, e, y0, y1);
    dst[e] = bits_to_normal(y0 ^ y1) * sdt;
  }
}

// ---------------- G1: H = tanh(A @ W1 + b1 + t*w1_last), M=64 ----------------
// grid 64 = 2fg x 32nt(32 cols). 512 thr = 8 waves (4m x 2n), wave frag 16x16.
// Barrier-free gather GEMM: 8 independent K-streams, frags straight from L2.
__global__ __launch_bounds__(512, 2) void g1_hidden(
    const u16* __restrict__ Abf, const u16* __restrict__ W1fT, const u16* __restrict__ W1gT,
    u16* __restrict__ Hf, u16* __restrict__ Hg,
    const float* __restrict__ b1f, const float* __restrict__ b1g,
    const float* __restrict__ W1fv, const float* __restrict__ W1gv,
    const float* __restrict__ tarr, int step) {
  const int bid = blockIdx.x;
  const int nt = bid & 31, fg = bid >> 5;
  const int n0 = nt * 32;
  const u16* __restrict__ W = fg ? W1gT : W1fT;
  const int tix = threadIdx.x, wid = tix >> 6, lane = tix & 63;
  const int lr = lane & 15, kg = lane >> 4;
  const int wm = (wid >> 1) * 16, wn = (wid & 1) * 16;

  const u16* pa = Abf + (size_t)(wm + lr) * 4096 + kg * 8;
  const u16* pb = W + (size_t)(n0 + wn + lr) * 4096 + kg * 8;

  f32x4 acc[8];
  bf16x8 av[8], bv[8];
  #pragma unroll
  for (int s = 0; s < 8; ++s) {
    acc[s] = (f32x4){0.f, 0.f, 0.f, 0.f};
    av[s] = *(const bf16x8*)(pa + s * 32);
    bv[s] = *(const bf16x8*)(pb + s * 32);
  }
  #pragma unroll
  for (int j = 0; j < 16; ++j) {
    #pragma unroll
    for (int s = 0; s < 8; ++s) {
      acc[s] = MFMA(av[s], bv[s], acc[s]);
      if (j + 1 < 16) {
        av[s] = *(const bf16x8*)(pa + (j + 1) * 256 + s * 32);
        bv[s] = *(const bf16x8*)(pb + (j + 1) * 256 + s * 32);
      }
    }
  }
  f32x4 tot = acc[0];
  #pragma unroll
  for (int s = 1; s < 8; ++s) tot += acc[s];

  const float tprev = tarr[step];
  const float* __restrict__ b1v = fg ? b1g : b1f;
  const float* __restrict__ wl = (fg ? W1gv : W1fv) + (size_t)4096 * 1024;
  u16* __restrict__ H = fg ? Hg : Hf;
  const int nc = n0 + wn + lr;
  const float c = b1v[nc] + tprev * wl[nc];
  const int mB = wm + kg * 4;
  #pragma unroll
  for (int r = 0; r < 4; ++r)
    H[(size_t)(mB + r) * 1024 + nc] = f2bf(tanhf(tot[r] + c));
}

// ---------------- G2: drift & diffusion GEMMs + SDE update, M=64 ----------------
// grid 64 nt(64 cols). 512 thr = 8 waves (4m x 2n), wave 16x32. f-pass + g-pass,
// 4 K-streams each, gather loads, no LDS/barriers.
__global__ __launch_bounds__(512, 2) void g2_update(
    const u16* __restrict__ Hf, const u16* __restrict__ Hg,
    const u16* __restrict__ W2fT, const u16* __restrict__ W2gT,
    const float* __restrict__ b2f, const float* __restrict__ b2g,
    float* __restrict__ A, u16* __restrict__ Abf,
    const float* __restrict__ dWstep, float* __restrict__ out,
    const float* __restrict__ tarr, int step) {
  const int nt = blockIdx.x;
  const int n0 = nt * 64;
  const int tix = threadIdx.x, wid = tix >> 6, lane = tix & 63;
  const int lr = lane & 15, kg = lane >> 4;
  const int wm = (wid >> 1) * 16, wn = (wid & 1) * 32;

  f32x4 CF[2], CG[2];
  {
    f32x4 accf[4][2], accg[4][2];
    bf16x8 av[4], b0v[4], b1v[4];
    // ---- f pass ----
    const u16* pa = Hf + (size_t)(wm + lr) * 1024 + kg * 8;
    const u16* pb0 = W2fT + (size_t)(n0 + wn + lr) * 1024 + kg * 8;
    const u16* pb1 = pb0 + 16 * 1024;
    #pragma unroll
    for (int s = 0; s < 4; ++s) {
      accf[s][0] = (f32x4){0.f, 0.f, 0.f, 0.f};
      accf[s][1] = (f32x4){0.f, 0.f, 0.f, 0.f};
      av[s] = *(const bf16x8*)(pa + s * 32);
      b0v[s] = *(const bf16x8*)(pb0 + s * 32);
      b1v[s] = *(const bf16x8*)(pb1 + s * 32);
    }
    #pragma unroll
    for (int j = 0; j < 8; ++j) {
      #pragma unroll
      for (int s = 0; s < 4; ++s) {
        accf[s][0] = MFMA(av[s], b0v[s], accf[s][0]);
        accf[s][1] = MFMA(av[s], b1v[s], accf[s][1]);
        if (j + 1 < 8) {
          av[s] = *(const bf16x8*)(pa + (j + 1) * 128 + s * 32);
          b0v[s] = *(const bf16x8*)(pb0 + (j + 1) * 128 + s * 32);
          b1v[s] = *(const bf16x8*)(pb1 + (j + 1) * 128 + s * 32);
        }
      }
    }
    // ---- g pass ----
    const u16* qa = Hg + (size_t)(wm + lr) * 1024 + kg * 8;
    const u16* qb0 = W2gT + (size_t)(n0 + wn + lr) * 1024 + kg * 8;
    const u16* qb1 = qb0 + 16 * 1024;
    #pragma unroll
    for (int s = 0; s < 4; ++s) {
      accg[s][0] = (f32x4){0.f, 0.f, 0.f, 0.f};
      accg[s][1] = (f32x4){0.f, 0.f, 0.f, 0.f};
      av[s] = *(const bf16x8*)(qa + s * 32);
      b0v[s] = *(const bf16x8*)(qb0 + s * 32);
      b1v[s] = *(const bf16x8*)(qb1 + s * 32);
    }
    #pragma unroll
    for (int j = 0; j < 8; ++j) {
      #pragma unroll
      for (int s = 0; s < 4; ++s) {
        accg[s][0] = MFMA(av[s], b0v[s], accg[s][0]);
        accg[s][1] = MFMA(av[s], b1v[s], accg[s][1]);
        if (j + 1 < 8) {
          av[s] = *(const bf16x8*)(qa + (j + 1) * 128 + s * 32);
          b0v[s] = *(const bf16x8*)(qb0 + (j + 1) * 128 + s * 32);
          b1v[s] = *(const bf16x8*)(qb1 + (j + 1) * 128 + s * 32);
        }
      }
    }
    #pragma unroll
    for (int f = 0; f < 2; ++f) {
      CF[f] = accf[0][f] + accf[1][f] + accf[2][f] + accf[3][f];
      CG[f] = accg[0][f] + accg[1][f] + accg[2][f] + accg[3][f];
    }
  }

  const float dt = tarr[1] - tarr[0];
  const int mB = wm + kg * 4;
  #pragma unroll
  for (int jf = 0; jf < 2; ++jf) {
    const f32x4 df = CF[jf], dg = CG[jf];
    const int nc = n0 + wn + jf * 16 + lr;
    const float bfv = b2f[nc], bgv = b2g[nc];
    #pragma unroll
    for (int r = 0; r < 4; ++r) {
      const int m = mB + r;
      const float drift = df[r] + bfv;
      const float graw = dg[r] + bgv;
      const float diff = fmaxf(graw, 0.0f) + log1pf(expf(-fabsf(graw)));  // softplus
      const int ai = m * 4096 + nc;
      const float aprev = A[ai];
      const float dw = dWstep[ai];
      const float anew = aprev + drift * dt + diff * dw;
      A[ai] = anew;
      Abf[ai] = f2bf(anew);
      const float sig = (nc % 65 == 0) ? 0.0f : 1.0f / (1.0f + expf(-anew));
      #pragma unroll
      for (int s = 0; s < 4; ++s)
        out[((size_t)(s * 64 + step + 1) * 64 + m) * 4096 + nc] = sig;
    }
  }
}

// ---------------- launch ----------------
extern "C" void kernel_launch(void* const* d_in, const int* in_sizes, int n_in,
                              void* d_out, int out_size, void* d_ws, size_t ws_size,
                              hipStream_t stream) {
  const float* A0 = (const float*)d_in[0];
  const float* tarr = (const float*)d_in[1];
  const float* W1f = (const float*)d_in[2];
  const float* b1f = (const float*)d_in[3];
  const float* W2f = (const float*)d_in[4];
  const float* b2f = (const float*)d_in[5];
  const float* W1g = (const float*)d_in[6];
  const float* b1g = (const float*)d_in[7];
  const float* W2g = (const float*)d_in[8];
  const float* b2g = (const float*)d_in[9];
  float* out = (float*)d_out;
  char* ws = (char*)d_ws;
  const size_t MB = 1024 * 1024;
  u16* W1fT = (u16*)(ws + 0 * MB);          // (1024,4096) bf16
  u16* W1gT = (u16*)(ws + 8 * MB);
  u16* W2fT = (u16*)(ws + 16 * MB);         // (4096,1024) bf16
  u16* W2gT = (u16*)(ws + 24 * MB);
  float* A  = (float*)(ws + 32 * MB);       // (64,4096) f32 state
  u16* Abf  = (u16*)(ws + 33 * MB);         // bf16 mirror
  u16* Hf   = (u16*)(ws + 34 * MB);         // (64,1024) bf16
  u16* Hg   = (u16*)(ws + 34 * MB + 512 * 1024);
  float* dWfb = (float*)(ws + 35 * MB);     // fallback single-step (1 MB)
  float* dWall = (float*)(ws + 36 * MB);    // 63 MB when available
  const bool pre = ws_size >= (size_t)100 * MB;

  s1_pack<<<dim3(64, 16, 4), 256, 0, stream>>>(W1f, W1g, W2f, W2g, W1fT, W1gT, W2fT, W2gT);
  s2_init<<<dim3(1024), 256, 0, stream>>>(A0, A, Abf, out);
  if (pre) dw_gen<<<dim3(63 * 32), 256, 0, stream>>>(tarr, dWall, -1);
  for (int i = 0; i < 63; ++i) {
    if (!pre) dw_gen<<<dim3(32), 256, 0, stream>>>(tarr, dWfb, i);
    g1_hidden<<<dim3(64), 512, 0, stream>>>(Abf, W1fT, W1gT, Hf, Hg, b1f, b1g,
                                            W1f, W1g, tarr, i);
    const float* dWstep = pre ? (dWall + (size_t)i * 262144) : dWfb;
    g2_update<<<dim3(64), 512, 0, stream>>>(Hf, Hg, W2fT, W2gT, b2f, b2g,
                                            A, Abf, dWstep, out, tarr, i);
  }
}